// Round 5
// baseline (177.802 us; speedup 1.0000x reference)
//
#include <hip/hip_runtime.h>

// The reference's einsum 'bnqk,bvnd->bnqd' contracts k and v INDEPENDENTLY:
//   qkv[b,n,q,d] = (sum_k attn[b,n,q,k]) * (sum_v vh[b,v,n,d]) = 1 * Vsum[b,n,d]
// so Q/K projections, mask and softmax all cancel (softmax rows sum to 1).
// With the faithful .view scramble, the pre-Wo matrix row l (within batch b) is
// Vproj[b][ (l/64)*64 + (j%64) ] (64-block repeated 16x), giving
//   out@Wo row l = M[b][l/64][:],  M[b][n][c] = sum_d Vproj[b][n*64+d]*WoSum[d][c]
//   WoSum[d][c] = sum_{qi<16} Wo[qi*64+d][c]
// Final: out[b,l,:] = LN( M[b][l/64,:] + q[b,l,:] ) * gamma + beta.

// ---------------- A: partial column-sum of v: part[b][slab][c] = sum of 64 rows
__global__ __launch_bounds__(256) void vreduce_kernel(const float* __restrict__ v,
                                                      float* __restrict__ part) {
    const int b = blockIdx.x, s = blockIdx.y, tid = threadIdx.x;
    float acc[4] = {0.f, 0.f, 0.f, 0.f};
    const size_t base = ((size_t)b * 1024 + s * 64) * 1024;
    for (int r = 0; r < 64; ++r) {
        const float* row = v + base + (size_t)r * 1024;
#pragma unroll
        for (int k = 0; k < 4; ++k) acc[k] += row[tid + k * 256];
    }
#pragma unroll
    for (int k = 0; k < 4; ++k)
        part[((size_t)b * 16 + s) * 1024 + tid + k * 256] = acc[k];
}

// ---------------- B: vsum = reduce(part); Vproj[b][j] = sum_i vsum[b][i]*Wv[i][j]
// grid 32 blocks (j-chunks of 32), block 128: thread = (j within chunk, i-quarter)
__global__ __launch_bounds__(128) void vproj_kernel(const float* __restrict__ part,
                                                    const float* __restrict__ Wv,
                                                    float* __restrict__ Vproj) {
    __shared__ float vs[4][1024];
    __shared__ float red[4][4][32];   // [quarter][b][j]
    const int tid = threadIdx.x;
    // build vsum in LDS (each of 4096 entries = sum of 16 slabs)
    for (int idx = tid; idx < 4096; idx += 128) {
        const int b = idx >> 10, i = idx & 1023;
        float s = 0.f;
#pragma unroll
        for (int sl = 0; sl < 16; ++sl) s += part[((size_t)b * 16 + sl) * 1024 + i];
        vs[b][i] = s;
    }
    __syncthreads();
    const int jl = tid & 31, qtr = tid >> 5;
    const int j = blockIdx.x * 32 + jl;
    float acc[4] = {0.f, 0.f, 0.f, 0.f};
    for (int i = qtr * 256; i < qtr * 256 + 256; ++i) {
        const float w = Wv[(size_t)i * 1024 + j];
#pragma unroll
        for (int b = 0; b < 4; ++b) acc[b] += vs[b][i] * w;
    }
#pragma unroll
    for (int b = 0; b < 4; ++b) red[qtr][b][jl] = acc[b];
    __syncthreads();
    if (qtr == 0) {
#pragma unroll
        for (int b = 0; b < 4; ++b)
            Vproj[(size_t)b * 1024 + j] = red[0][b][jl] + red[1][b][jl] + red[2][b][jl] + red[3][b][jl];
    }
}

// ---------------- C1: WoSum[d][c] = sum_{qi<16} Wo[qi*64+d][c]
__global__ __launch_bounds__(128) void wosum_kernel(const float* __restrict__ Wo,
                                                    float* __restrict__ WoSum) {
    const int c = blockIdx.x * 128 + threadIdx.x;
    for (int d = 0; d < 64; ++d) {
        float s = 0.f;
#pragma unroll
        for (int qi = 0; qi < 16; ++qi) s += Wo[(size_t)(qi * 64 + d) * 1024 + c];
        WoSum[(size_t)d * 1024 + c] = s;
    }
}

// ---------------- C2: M[bn][c] = sum_d Vproj[b][n*64+d] * WoSum[d][c]
__global__ __launch_bounds__(128) void mmat_kernel(const float* __restrict__ Vproj,
                                                   const float* __restrict__ WoSum,
                                                   float* __restrict__ M) {
    const int c = blockIdx.x * 128 + threadIdx.x;
    const int bn = blockIdx.y;                 // 0..63
    const int b = bn >> 4, n = bn & 15;
    float acc = 0.f;
#pragma unroll 8
    for (int d = 0; d < 64; ++d)
        acc += Vproj[(size_t)b * 1024 + n * 64 + d] * WoSum[(size_t)d * 1024 + c];
    M[(size_t)bn * 1024 + c] = acc;
}

// ---------------- D: fused residual + LayerNorm
__global__ __launch_bounds__(256) void ln_kernel(const float* __restrict__ M,
                                                 const float* __restrict__ qin,
                                                 const float* __restrict__ g,
                                                 const float* __restrict__ bta,
                                                 float* __restrict__ out) {
    const int row = blockIdx.x, tid = threadIdx.x;
    const int b = row >> 10, l = row & 1023, n = l >> 6;
    const float4 mv = ((const float4*)(M + ((size_t)b * 16 + n) * 1024))[tid];
    const float4 qv = ((const float4*)(qin + (size_t)row * 1024))[tid];
    float4 x;
    x.x = mv.x + qv.x; x.y = mv.y + qv.y; x.z = mv.z + qv.z; x.w = mv.w + qv.w;
    float s = x.x + x.y + x.z + x.w;
    float q2 = x.x * x.x + x.y * x.y + x.z * x.z + x.w * x.w;
#pragma unroll
    for (int d = 1; d < 64; d <<= 1) { s += __shfl_xor(s, d); q2 += __shfl_xor(q2, d); }
    __shared__ float rs[4], rq[4];
    const int w = tid >> 6, lane = tid & 63;
    if (lane == 0) { rs[w] = s; rq[w] = q2; }
    __syncthreads();
    s  = rs[0] + rs[1] + rs[2] + rs[3];
    q2 = rq[0] + rq[1] + rq[2] + rq[3];
    const float mu = s * (1.f / 1024.f);
    const float var = q2 * (1.f / 1024.f) - mu * mu;
    const float rstd = rsqrtf(var + 1e-6f);
    const float4 gg = ((const float4*)g)[tid];
    const float4 bb = ((const float4*)bta)[tid];
    float4 o;
    o.x = (x.x - mu) * rstd * gg.x + bb.x;
    o.y = (x.y - mu) * rstd * gg.y + bb.y;
    o.z = (x.z - mu) * rstd * gg.z + bb.z;
    o.w = (x.w - mu) * rstd * gg.w + bb.w;
    ((float4*)(out + (size_t)row * 1024))[tid] = o;
}

// ---------------- launch
extern "C" void kernel_launch(void* const* d_in, const int* in_sizes, int n_in,
                              void* d_out, int out_size, void* d_ws, size_t ws_size,
                              hipStream_t stream) {
    const float* q    = (const float*)d_in[0];
    const float* v    = (const float*)d_in[2];
    const float* Wv   = (const float*)d_in[6];
    const float* Wo   = (const float*)d_in[7];
    const float* gamma= (const float*)d_in[8];
    const float* beta = (const float*)d_in[9];
    float* out = (float*)d_out;

    // workspace: part 256 KB | Vproj 16 KB | WoSum 256 KB | M 1 MB  (< 2 MB total)
    float* part  = (float*)d_ws;                 // [4][16][1024]
    float* Vproj = part  + 4 * 16 * 1024;        // [4][1024]
    float* WoSum = Vproj + 4 * 1024;             // [64][1024]
    float* M     = WoSum + 64 * 1024;            // [64][1024]  (bn-major)

    vreduce_kernel<<<dim3(4, 16), 256, 0, stream>>>(v, part);
    vproj_kernel<<<32, 128, 0, stream>>>(part, Wv, Vproj);
    wosum_kernel<<<8, 128, 0, stream>>>(Wo, WoSum);
    mmat_kernel<<<dim3(8, 64), 128, 0, stream>>>(Vproj, WoSum, M);
    ln_kernel<<<4096, 256, 0, stream>>>(M, q, gamma, beta, out);
}

// Round 6
// 133.477 us; speedup vs baseline: 1.3321x; 1.3321x over previous
//
#include <hip/hip_runtime.h>

// The reference's einsum 'bnqk,bvnd->bnqd' contracts k and v INDEPENDENTLY:
//   qkv[b,n,q,d] = (sum_k attn[b,n,q,k]) * (sum_v vh[b,v,n,d]) = 1 * Vsum[b,n,d]
// so Q/K projections, mask and softmax all cancel (softmax rows sum to 1).
// With the faithful .view scramble, the pre-Wo matrix row l (within batch b) is
// Vproj[b][ (l/64)*64 + (j%64) ] (64-block repeated 16x), giving
//   out@Wo row l = M[b][l/64][:],  M[b][n][c] = sum_d Vproj[b][n*64+d]*WoSum[d][c]
//   WoSum[d][c] = sum_{qi<16} Wo[qi*64+d][c]
// Final: out[b,l,:] = LN( M[b][l/64,:] + q[b,l,:] ) * gamma + beta.
//
// R5 -> R6: same algebra, all kernels re-gridded for coalescing + parallelism
// (wosum was 45us at 0.6% HBM: 8 blocks, 4KB-strided reads).

// ---------------- A: part[b][s][c] = sum of 16 rows of v  (grid 4x64=256 blocks)
__global__ __launch_bounds__(256) void vreduce_kernel(const float* __restrict__ v,
                                                      float* __restrict__ part) {
    const int b = blockIdx.x, s = blockIdx.y, tid = threadIdx.x;
    float acc[4] = {0.f, 0.f, 0.f, 0.f};
    const size_t base = ((size_t)b * 1024 + s * 16) * 1024;
    for (int r = 0; r < 16; ++r) {
        const float* row = v + base + (size_t)r * 1024;
#pragma unroll
        for (int k = 0; k < 4; ++k) acc[k] += row[tid + k * 256];
    }
#pragma unroll
    for (int k = 0; k < 4; ++k)
        part[((size_t)b * 64 + s) * 1024 + tid + k * 256] = acc[k];
}

// ---------------- B: Vpart[g][b][j] = sum_{i in group g} vsum[b][i] * Wv[i][j]
// grid (4 j-chunks x 16 i-groups) = 64 blocks, 256 threads. Wv read as
// contiguous 1KB row segments (j across threads, i in loop).
__global__ __launch_bounds__(256) void vproj_kernel(const float* __restrict__ part,
                                                    const float* __restrict__ Wv,
                                                    float* __restrict__ Vpart) {
    __shared__ float vs[4][64];
    const int tid = threadIdx.x;
    const int jc = blockIdx.x, ig = blockIdx.y;
    // vs[b][il] = vsum[b][ig*64+il] = sum_s part[b][s][i]
    {
        const int b = tid >> 6, il = tid & 63;
        const int i = ig * 64 + il;
        float s = 0.f;
        for (int sl = 0; sl < 64; ++sl) s += part[((size_t)b * 64 + sl) * 1024 + i];
        vs[b][il] = s;
    }
    __syncthreads();
    const int j = jc * 256 + tid;
    float acc[4] = {0.f, 0.f, 0.f, 0.f};
    for (int il = 0; il < 64; ++il) {
        const float w = Wv[(size_t)(ig * 64 + il) * 1024 + j];
#pragma unroll
        for (int b = 0; b < 4; ++b) acc[b] += vs[b][il] * w;
    }
#pragma unroll
    for (int b = 0; b < 4; ++b)
        Vpart[((size_t)ig * 4 + b) * 1024 + j] = acc[b];
}

// ---------------- C1: WoSum[d][c] = sum_{qi<16} Wo[qi*64+d][c]
// grid (4 c-chunks x 64 d) = 256 blocks; 16 coalesced 1KB row segments each.
__global__ __launch_bounds__(256) void wosum_kernel(const float* __restrict__ Wo,
                                                    float* __restrict__ WoSum) {
    const int c = blockIdx.x * 256 + threadIdx.x;
    const int d = blockIdx.y;
    float s = 0.f;
#pragma unroll
    for (int qi = 0; qi < 16; ++qi) s += Wo[(size_t)(qi * 64 + d) * 1024 + c];
    WoSum[(size_t)d * 1024 + c] = s;
}

// ---------------- C2: M[bn][c] = sum_d Vproj[b][n*64+d] * WoSum[d][c]
// grid (4 c-chunks x 64 bn) = 256 blocks; WoSum read as coalesced rows.
__global__ __launch_bounds__(256) void mmat_kernel(const float* __restrict__ Vpart,
                                                   const float* __restrict__ WoSum,
                                                   float* __restrict__ M) {
    __shared__ float vp[64];
    const int tid = threadIdx.x;
    const int bn = blockIdx.y;                 // == b*16 + n
    const int b = bn >> 4, n = bn & 15;
    if (tid < 64) {                            // Vproj[b][n*64+tid] = sum of 16 partials
        float s = 0.f;
#pragma unroll
        for (int g = 0; g < 16; ++g)
            s += Vpart[((size_t)g * 4 + b) * 1024 + n * 64 + tid];
        vp[tid] = s;
    }
    __syncthreads();
    const int c = blockIdx.x * 256 + tid;
    float acc = 0.f;
#pragma unroll 8
    for (int d = 0; d < 64; ++d)
        acc += vp[d] * WoSum[(size_t)d * 1024 + c];
    M[(size_t)bn * 1024 + c] = acc;
}

// ---------------- D: fused residual + LayerNorm
__global__ __launch_bounds__(256) void ln_kernel(const float* __restrict__ M,
                                                 const float* __restrict__ qin,
                                                 const float* __restrict__ g,
                                                 const float* __restrict__ bta,
                                                 float* __restrict__ out) {
    const int row = blockIdx.x, tid = threadIdx.x;
    const int b = row >> 10, l = row & 1023, n = l >> 6;
    const float4 mv = ((const float4*)(M + ((size_t)b * 16 + n) * 1024))[tid];
    const float4 qv = ((const float4*)(qin + (size_t)row * 1024))[tid];
    float4 x;
    x.x = mv.x + qv.x; x.y = mv.y + qv.y; x.z = mv.z + qv.z; x.w = mv.w + qv.w;
    float s = x.x + x.y + x.z + x.w;
    float q2 = x.x * x.x + x.y * x.y + x.z * x.z + x.w * x.w;
#pragma unroll
    for (int d = 1; d < 64; d <<= 1) { s += __shfl_xor(s, d); q2 += __shfl_xor(q2, d); }
    __shared__ float rs[4], rq[4];
    const int w = tid >> 6, lane = tid & 63;
    if (lane == 0) { rs[w] = s; rq[w] = q2; }
    __syncthreads();
    s  = rs[0] + rs[1] + rs[2] + rs[3];
    q2 = rq[0] + rq[1] + rq[2] + rq[3];
    const float mu = s * (1.f / 1024.f);
    const float var = q2 * (1.f / 1024.f) - mu * mu;
    const float rstd = rsqrtf(var + 1e-6f);
    const float4 gg = ((const float4*)g)[tid];
    const float4 bb = ((const float4*)bta)[tid];
    float4 o;
    o.x = (x.x - mu) * rstd * gg.x + bb.x;
    o.y = (x.y - mu) * rstd * gg.y + bb.y;
    o.z = (x.z - mu) * rstd * gg.z + bb.z;
    o.w = (x.w - mu) * rstd * gg.w + bb.w;
    ((float4*)(out + (size_t)row * 1024))[tid] = o;
}

// ---------------- launch
extern "C" void kernel_launch(void* const* d_in, const int* in_sizes, int n_in,
                              void* d_out, int out_size, void* d_ws, size_t ws_size,
                              hipStream_t stream) {
    const float* q    = (const float*)d_in[0];
    const float* v    = (const float*)d_in[2];
    const float* Wv   = (const float*)d_in[6];
    const float* Wo   = (const float*)d_in[7];
    const float* gamma= (const float*)d_in[8];
    const float* beta = (const float*)d_in[9];
    float* out = (float*)d_out;

    // workspace: part 1 MB | Vpart 256 KB | WoSum 256 KB | M 1 MB  (< 3 MB total)
    float* part  = (float*)d_ws;                 // [4][64][1024]
    float* Vpart = part  + 4 * 64 * 1024;        // [16][4][1024]
    float* WoSum = Vpart + 16 * 4 * 1024;        // [64][1024]
    float* M     = WoSum + 64 * 1024;            // [64][1024]  (bn-major)

    vreduce_kernel<<<dim3(4, 64), 256, 0, stream>>>(v, part);
    vproj_kernel<<<dim3(4, 16), 256, 0, stream>>>(part, Wv, Vpart);
    wosum_kernel<<<dim3(4, 64), 256, 0, stream>>>(Wo, WoSum);
    mmat_kernel<<<dim3(4, 64), 256, 0, stream>>>(Vpart, WoSum, M);
    ln_kernel<<<4096, 256, 0, stream>>>(M, q, gamma, beta, out);
}

// Round 7
// 131.481 us; speedup vs baseline: 1.3523x; 1.0152x over previous
//
#include <hip/hip_runtime.h>

// The reference's einsum 'bnqk,bvnd->bnqd' contracts k and v INDEPENDENTLY:
//   qkv[b,n,q,d] = (sum_k attn[b,n,q,k]) * (sum_v vh[b,v,n,d]) = 1 * Vsum[b,n,d]
// so Q/K projections, mask and softmax all cancel (softmax rows sum to 1).
// With the faithful .view scramble, the pre-Wo matrix row l (within batch b) is
// Vproj[b][ (l/64)*64 + (j%64) ] (64-block repeated 16x), giving
//   out@Wo row l = M[b][l/64][:],  M[b][n][c] = sum_d Vproj[b][n*64+d]*WoSum[d][c]
//   WoSum[d][c] = sum_{qi<16} Wo[qi*64+d][c]
// Final: out[b,l,:] = LN( M[b][l/64,:] + q[b,l,:] ) * gamma + beta.
//
// R6 -> R7: fuse vreduce+wosum (independent stages) into one 512-block kernel,
// float4 loads in the v reduction. 4 kernels total. Probing whether the
// residual ~130us is harness poison/restore (my kernels sum to ~15-20us).

// ---------------- S1: blocks 0..255: part[b][s][c] = sum of 16 rows of v
//                      blocks 256..511: WoSum[d][c] = sum_{qi<16} Wo[qi*64+d][c]
__global__ __launch_bounds__(256) void stage1_kernel(const float* __restrict__ v,
                                                     const float* __restrict__ Wo,
                                                     float* __restrict__ part,
                                                     float* __restrict__ WoSum) {
    const int blk = blockIdx.x, tid = threadIdx.x;
    if (blk < 256) {
        const int b = blk >> 6, s = blk & 63;
        const size_t base = ((size_t)b * 1024 + s * 16) * 1024;
        float4 acc = {0.f, 0.f, 0.f, 0.f};
        for (int r = 0; r < 16; ++r) {
            const float4 x = ((const float4*)(v + base + (size_t)r * 1024))[tid];
            acc.x += x.x; acc.y += x.y; acc.z += x.z; acc.w += x.w;
        }
        ((float4*)(part + ((size_t)b * 64 + s) * 1024))[tid] = acc;
    } else {
        const int qb = blk - 256;              // 0..255
        const int d = qb >> 2;
        const int c = (qb & 3) * 256 + tid;
        float s = 0.f;
#pragma unroll
        for (int qi = 0; qi < 16; ++qi) s += Wo[(size_t)(qi * 64 + d) * 1024 + c];
        WoSum[(size_t)d * 1024 + c] = s;
    }
}

// ---------------- S2: Vpart[g][b][j] = sum_{i in group g} vsum[b][i] * Wv[i][j]
// grid (4 j-chunks x 16 i-groups) = 64 blocks, 256 threads. Wv read as
// contiguous 1KB row segments (j across threads, i in loop).
__global__ __launch_bounds__(256) void vproj_kernel(const float* __restrict__ part,
                                                    const float* __restrict__ Wv,
                                                    float* __restrict__ Vpart) {
    __shared__ float vs[4][64];
    const int tid = threadIdx.x;
    const int jc = blockIdx.x, ig = blockIdx.y;
    // vs[b][il] = vsum[b][ig*64+il] = sum_s part[b][s][i]
    {
        const int b = tid >> 6, il = tid & 63;
        const int i = ig * 64 + il;
        float s = 0.f;
        for (int sl = 0; sl < 64; ++sl) s += part[((size_t)b * 64 + sl) * 1024 + i];
        vs[b][il] = s;
    }
    __syncthreads();
    const int j = jc * 256 + tid;
    float acc[4] = {0.f, 0.f, 0.f, 0.f};
    for (int il = 0; il < 64; ++il) {
        const float w = Wv[(size_t)(ig * 64 + il) * 1024 + j];
#pragma unroll
        for (int b = 0; b < 4; ++b) acc[b] += vs[b][il] * w;
    }
#pragma unroll
    for (int b = 0; b < 4; ++b)
        Vpart[((size_t)ig * 4 + b) * 1024 + j] = acc[b];
}

// ---------------- S3: M[bn][c] = sum_d Vproj[b][n*64+d] * WoSum[d][c]
// grid (4 c-chunks x 64 bn) = 256 blocks; WoSum read as coalesced rows.
__global__ __launch_bounds__(256) void mmat_kernel(const float* __restrict__ Vpart,
                                                   const float* __restrict__ WoSum,
                                                   float* __restrict__ M) {
    __shared__ float vp[64];
    const int tid = threadIdx.x;
    const int bn = blockIdx.y;                 // == b*16 + n
    const int b = bn >> 4, n = bn & 15;
    if (tid < 64) {                            // Vproj[b][n*64+tid] = sum of 16 partials
        float s = 0.f;
#pragma unroll
        for (int g = 0; g < 16; ++g)
            s += Vpart[((size_t)g * 4 + b) * 1024 + n * 64 + tid];
        vp[tid] = s;
    }
    __syncthreads();
    const int c = blockIdx.x * 256 + tid;
    float acc = 0.f;
#pragma unroll 8
    for (int d = 0; d < 64; ++d)
        acc += vp[d] * WoSum[(size_t)d * 1024 + c];
    M[(size_t)bn * 1024 + c] = acc;
}

// ---------------- S4: fused residual + LayerNorm
__global__ __launch_bounds__(256) void ln_kernel(const float* __restrict__ M,
                                                 const float* __restrict__ qin,
                                                 const float* __restrict__ g,
                                                 const float* __restrict__ bta,
                                                 float* __restrict__ out) {
    const int row = blockIdx.x, tid = threadIdx.x;
    const int b = row >> 10, l = row & 1023, n = l >> 6;
    const float4 mv = ((const float4*)(M + ((size_t)b * 16 + n) * 1024))[tid];
    const float4 qv = ((const float4*)(qin + (size_t)row * 1024))[tid];
    float4 x;
    x.x = mv.x + qv.x; x.y = mv.y + qv.y; x.z = mv.z + qv.z; x.w = mv.w + qv.w;
    float s = x.x + x.y + x.z + x.w;
    float q2 = x.x * x.x + x.y * x.y + x.z * x.z + x.w * x.w;
#pragma unroll
    for (int d = 1; d < 64; d <<= 1) { s += __shfl_xor(s, d); q2 += __shfl_xor(q2, d); }
    __shared__ float rs[4], rq[4];
    const int w = tid >> 6, lane = tid & 63;
    if (lane == 0) { rs[w] = s; rq[w] = q2; }
    __syncthreads();
    s  = rs[0] + rs[1] + rs[2] + rs[3];
    q2 = rq[0] + rq[1] + rq[2] + rq[3];
    const float mu = s * (1.f / 1024.f);
    const float var = q2 * (1.f / 1024.f) - mu * mu;
    const float rstd = rsqrtf(var + 1e-6f);
    const float4 gg = ((const float4*)g)[tid];
    const float4 bb = ((const float4*)bta)[tid];
    float4 o;
    o.x = (x.x - mu) * rstd * gg.x + bb.x;
    o.y = (x.y - mu) * rstd * gg.y + bb.y;
    o.z = (x.z - mu) * rstd * gg.z + bb.z;
    o.w = (x.w - mu) * rstd * gg.w + bb.w;
    ((float4*)(out + (size_t)row * 1024))[tid] = o;
}

// ---------------- launch
extern "C" void kernel_launch(void* const* d_in, const int* in_sizes, int n_in,
                              void* d_out, int out_size, void* d_ws, size_t ws_size,
                              hipStream_t stream) {
    const float* q    = (const float*)d_in[0];
    const float* v    = (const float*)d_in[2];
    const float* Wv   = (const float*)d_in[6];
    const float* Wo   = (const float*)d_in[7];
    const float* gamma= (const float*)d_in[8];
    const float* beta = (const float*)d_in[9];
    float* out = (float*)d_out;

    // workspace: part 1 MB | Vpart 256 KB | WoSum 256 KB | M 256 KB
    float* part  = (float*)d_ws;                 // [4][64][1024]
    float* Vpart = part  + 4 * 64 * 1024;        // [16][4][1024]
    float* WoSum = Vpart + 16 * 4 * 1024;        // [64][1024]
    float* M     = WoSum + 64 * 1024;            // [64][1024]  (bn-major)

    stage1_kernel<<<512, 256, 0, stream>>>(v, Wo, part, WoSum);
    vproj_kernel<<<dim3(4, 16), 256, 0, stream>>>(part, Wv, Vpart);
    mmat_kernel<<<dim3(4, 64), 256, 0, stream>>>(Vpart, WoSum, M);
    ln_kernel<<<4096, 256, 0, stream>>>(M, q, gamma, beta, out);
}